// Round 1
// baseline (96.216 us; speedup 1.0000x reference)
//
#include <hip/hip_runtime.h>

#define BS_ROWS 1048576
#define CLA 32
#define NBINS 10

// Pass 1: per-row g + BCE mean, reduced into a 10-bin histogram
// (counts + sum of per-row BCE means per bin).
// Mapping: 8 lanes per row, each lane loads one float4 (4 classes).
// A 64-lane wave covers 8 rows = 1 KiB contiguous per array -> coalesced.
__global__ __launch_bounds__(256) void ghm_pass1(
    const float* __restrict__ in, const float* __restrict__ tg,
    float* __restrict__ cnt, float* __restrict__ bsum)
{
    __shared__ float s_cnt[NBINS];
    __shared__ float s_bsum[NBINS];
    const int tid = threadIdx.x;
    if (tid < NBINS) { s_cnt[tid] = 0.0f; s_bsum[tid] = 0.0f; }
    __syncthreads();

    const int sub = tid & 7;                   // which float4 of the row
    const int rows_per_block = 256 / 8;        // 32 rows per block-iteration
    const long long stride = (long long)gridDim.x * rows_per_block;

    for (long long row = (long long)blockIdx.x * rows_per_block + (tid >> 3);
         row < BS_ROWS; row += stride)
    {
        const float4 iv = *((const float4*)(in + row * CLA) + sub);
        const float4 tv = *((const float4*)(tg + row * CLA) + sub);

        float gs = fabsf(iv.x - tv.x) + fabsf(iv.y - tv.y)
                 + fabsf(iv.z - tv.z) + fabsf(iv.w - tv.w);

        // targets are exactly 0.0 / 1.0 (bernoulli -> float):
        // BCE elem = -( t*log(p) + (1-t)*log1p(-p) ) = -log(t ? p : 1-p)
        float a0 = tv.x > 0.5f ? iv.x : 1.0f - iv.x;
        float a1 = tv.y > 0.5f ? iv.y : 1.0f - iv.y;
        float a2 = tv.z > 0.5f ? iv.z : 1.0f - iv.z;
        float a3 = tv.w > 0.5f ? iv.w : 1.0f - iv.w;
        float bs = -(__logf(a0) + __logf(a1) + __logf(a2) + __logf(a3));

        // reduce across the 8-lane group sharing this row
        #pragma unroll
        for (int off = 1; off < 8; off <<= 1) {
            gs += __shfl_xor(gs, off);
            bs += __shfl_xor(bs, off);
        }

        if (sub == 0) {
            float g = gs * (1.0f / 32.0f);
            int idx = (int)floorf(g * 10.0f);
            idx = idx < 0 ? 0 : (idx > NBINS - 1 ? NBINS - 1 : idx);
            atomicAdd(&s_cnt[idx], 1.0f);
            atomicAdd(&s_bsum[idx], bs * (1.0f / 32.0f));
        }
    }
    __syncthreads();
    if (tid < NBINS) {
        atomicAdd(&cnt[tid], s_cnt[tid]);
        atomicAdd(&bsum[tid], s_bsum[tid]);
    }
}

// Pass 2: finalize from the 10-bin statistics. Single thread, double math.
// sum(w) over rows == sum_b counts[b] * pbw[b]^2  (all rows in a bin share w).
__global__ void ghm_pass2(const float* __restrict__ cnt,
                          const float* __restrict__ bsum,
                          float* __restrict__ out)
{
    if (threadIdx.x == 0 && blockIdx.x == 0) {
        const double tot = (double)BS_ROWS * (double)CLA;
        // smooth = 1 - 25*(b/10)^2, zeroed for b >= 2: {1.0, 0.75, 0, ...}
        const float smooth[NBINS] = {1.0f, 0.75f, 0,0,0,0,0,0,0,0};
        double pbw2[NBINS];
        double sum_w = 0.0;
        for (int b = 0; b < NBINS; ++b) {
            double c = (double)cnt[b];
            double pbw = (c > 0.0 && smooth[b] > 0.0f)
                       ? (double)smooth[b] * tot / (0.25 * c) : 0.0;
            pbw2[b] = pbw * pbw;
            sum_w += c * pbw2[b];
        }
        double loss = 0.0;
        for (int b = 0; b < NBINS; ++b) {
            double w = (sum_w > 0.0) ? pbw2[b] / sum_w : 0.0;
            if (w < 1e-6) w = 0.0;      // reference: w = where(w < 1e-6, 0, w)
            loss += (double)bsum[b] * w;
        }
        out[0] = (float)loss;
    }
}

extern "C" void kernel_launch(void* const* d_in, const int* in_sizes, int n_in,
                              void* d_out, int out_size, void* d_ws, size_t ws_size,
                              hipStream_t stream) {
    const float* in = (const float*)d_in[0];   // inputs  [BS, CLA] f32
    const float* tg = (const float*)d_in[1];   // targets [BS, CLA] f32
    float* ws   = (float*)d_ws;
    float* cnt  = ws;                          // [10]
    float* bsum = ws + NBINS;                  // [10]

    // ws is poisoned (0xAA) and never re-poisoned between replays: zero it
    // ourselves every call (graph-capture-legal memset node).
    hipMemsetAsync(d_ws, 0, 2 * NBINS * sizeof(float), stream);

    ghm_pass1<<<2048, 256, 0, stream>>>(in, tg, cnt, bsum);
    ghm_pass2<<<1, 64, 0, stream>>>(cnt, bsum, (float*)d_out);
}

// Round 2
// 83.647 us; speedup vs baseline: 1.1503x; 1.1503x over previous
//
#include <hip/hip_runtime.h>

#define BS_ROWS 1048576
#define CLA 32
#define NBINS 10
#define GRID 2048
#define RPB 32              // rows per block-slice (256 thr / 8 lanes-per-row)
#define BATCH 4             // row-slices processed per outer iteration
#define OUTER 4             // GRID*RPB*BATCH*OUTER == BS_ROWS exactly

// Pass 1: per-row g + BCE mean -> 10-bin histogram (counts + bce-sum per bin).
// 8 lanes per row, one float4 per lane; wave covers 8 rows = 1 KiB contiguous.
// BATCH row-slices are loaded back-to-back (8 loads in flight) before compute,
// and the 4 shfl-reduce chains overlap each other's latency.
__global__ __launch_bounds__(256) void ghm_pass1(
    const float* __restrict__ in, const float* __restrict__ tg,
    float* __restrict__ cnt, float* __restrict__ bsum)
{
    __shared__ float s_cnt[NBINS];
    __shared__ float s_bsum[NBINS];
    const int tid = threadIdx.x;
    if (tid < NBINS) { s_cnt[tid] = 0.0f; s_bsum[tid] = 0.0f; }
    __syncthreads();

    const unsigned sub = tid & 7;               // which float4 of the row
    const unsigned rg  = tid >> 3;              // row within slice
    const unsigned row0 = blockIdx.x * RPB + rg;
    const unsigned sstride = GRID * RPB;        // 65536 rows between slices

    #pragma unroll 1
    for (int outer = 0; outer < OUTER; ++outer) {
        const unsigned rbase = row0 + (unsigned)outer * (sstride * BATCH);

        float4 iv[BATCH], tv[BATCH];
        #pragma unroll
        for (int j = 0; j < BATCH; ++j) {
            const unsigned off = (rbase + j * sstride) * CLA + sub * 4;
            iv[j] = *(const float4*)(in + off);
            tv[j] = *(const float4*)(tg + off);
        }

        float gs[BATCH], bs[BATCH];
        #pragma unroll
        for (int j = 0; j < BATCH; ++j) {
            gs[j] = fabsf(iv[j].x - tv[j].x) + fabsf(iv[j].y - tv[j].y)
                  + fabsf(iv[j].z - tv[j].z) + fabsf(iv[j].w - tv[j].w);
            // targets are exactly 0.0/1.0: BCE elem = -log(t ? p : 1-p)
            float a0 = tv[j].x > 0.5f ? iv[j].x : 1.0f - iv[j].x;
            float a1 = tv[j].y > 0.5f ? iv[j].y : 1.0f - iv[j].y;
            float a2 = tv[j].z > 0.5f ? iv[j].z : 1.0f - iv[j].z;
            float a3 = tv[j].w > 0.5f ? iv[j].w : 1.0f - iv[j].w;
            bs[j] = -(__logf(a0) + __logf(a1) + __logf(a2) + __logf(a3));
        }

        // 4 independent 3-level reductions across the 8-lane row groups;
        // chains interleave so ds_swizzle latency overlaps.
        #pragma unroll
        for (int off = 1; off < 8; off <<= 1) {
            #pragma unroll
            for (int j = 0; j < BATCH; ++j) {
                gs[j] += __shfl_xor(gs[j], off);
                bs[j] += __shfl_xor(bs[j], off);
            }
        }

        if (sub == 0) {
            #pragma unroll
            for (int j = 0; j < BATCH; ++j) {
                float g = gs[j] * (1.0f / 32.0f);
                int idx = (int)floorf(g * 10.0f);
                idx = idx < 0 ? 0 : (idx > NBINS - 1 ? NBINS - 1 : idx);
                atomicAdd(&s_cnt[idx], 1.0f);
                atomicAdd(&s_bsum[idx], bs[j] * (1.0f / 32.0f));
            }
        }
    }
    __syncthreads();
    if (tid < NBINS) {
        atomicAdd(&cnt[tid], s_cnt[tid]);
        atomicAdd(&bsum[tid], s_bsum[tid]);
    }
}

// Pass 2: finalize from the 10-bin statistics. Single thread, double math.
// sum(w) over rows == sum_b counts[b] * pbw[b]^2 (all rows in a bin share w).
__global__ void ghm_pass2(const float* __restrict__ cnt,
                          const float* __restrict__ bsum,
                          float* __restrict__ out)
{
    if (threadIdx.x == 0 && blockIdx.x == 0) {
        const double tot = (double)BS_ROWS * (double)CLA;
        // smooth = 1 - 25*(b/10)^2, zeroed for b >= 2: {1.0, 0.75, 0...}
        const float smooth[NBINS] = {1.0f, 0.75f, 0,0,0,0,0,0,0,0};
        double pbw2[NBINS];
        double sum_w = 0.0;
        for (int b = 0; b < NBINS; ++b) {
            double c = (double)cnt[b];
            double pbw = (c > 0.0 && smooth[b] > 0.0f)
                       ? (double)smooth[b] * tot / (0.25 * c) : 0.0;
            pbw2[b] = pbw * pbw;
            sum_w += c * pbw2[b];
        }
        double loss = 0.0;
        for (int b = 0; b < NBINS; ++b) {
            double w = (sum_w > 0.0) ? pbw2[b] / sum_w : 0.0;
            if (w < 1e-6) w = 0.0;   // reference: w = where(w < 1e-6, 0, w)
            loss += (double)bsum[b] * w;
        }
        out[0] = (float)loss;
    }
}

extern "C" void kernel_launch(void* const* d_in, const int* in_sizes, int n_in,
                              void* d_out, int out_size, void* d_ws, size_t ws_size,
                              hipStream_t stream) {
    const float* in = (const float*)d_in[0];   // inputs  [BS, CLA] f32
    const float* tg = (const float*)d_in[1];   // targets [BS, CLA] f32
    float* ws   = (float*)d_ws;
    float* cnt  = ws;                          // [10]
    float* bsum = ws + NBINS;                  // [10]

    // ws is poisoned (0xAA) and never re-poisoned between replays: zero it
    // ourselves every call (graph-capture-legal memset node).
    hipMemsetAsync(d_ws, 0, 2 * NBINS * sizeof(float), stream);

    ghm_pass1<<<GRID, 256, 0, stream>>>(in, tg, cnt, bsum);
    ghm_pass2<<<1, 64, 0, stream>>>(cnt, bsum, (float*)d_out);
}

// Round 3
// 82.119 us; speedup vs baseline: 1.1717x; 1.0186x over previous
//
#include <hip/hip_runtime.h>

#define BS_ROWS 1048576
#define CLA 32
#define NBINS 10
#define GRID 2048
#define RPB 512            // contiguous rows per block  (GRID*RPB == BS_ROWS)
#define RROWS 256          // rows per round (== blockDim)
#define NROUNDS 2          // RPB / RROWS
#define LN2 0.69314718055994531f

// Pass 1, restructured: per 256-row round,
//  Phase A (streaming): each thread handles one float4 (quarter-row segment)
//    per iter: 2 coalesced float4 loads -> ~25 VALU -> 2 LDS writes.
//    No cross-lane ops, no atomics; iterations independent; loads grouped
//    4 iters at a time in statically-indexed arrays for MLP.
//  Phase B (tiny): after one barrier, thread t sums row t's 8 partials from
//    padded LDS (stride 9 -> conflict-free), bins, 2 LDS atomics.
__global__ __launch_bounds__(256) void ghm_pass1(
    const float* __restrict__ in, const float* __restrict__ tg,
    float* __restrict__ cnt, float* __restrict__ bsum)
{
    __shared__ float gpart[RROWS][9];   // +1 pad: phase-B reads conflict-free
    __shared__ float bpart[RROWS][9];
    __shared__ float s_cnt[NBINS];
    __shared__ float s_bsum[NBINS];

    const int tid = threadIdx.x;
    if (tid < NBINS) { s_cnt[tid] = 0.0f; s_bsum[tid] = 0.0f; }
    // (no sync needed: hist first touched in phase B, after a barrier)

    const float4* __restrict__ in4 = (const float4*)in;
    const float4* __restrict__ tg4 = (const float4*)tg;
    const unsigned blk4 = blockIdx.x * (RPB * CLA / 4);   // float4 base of block

    #pragma unroll
    for (int r = 0; r < NROUNDS; ++r) {
        const unsigned base4 = blk4 + r * (RROWS * CLA / 4);

        // ---- Phase A: 8 float4-iters, in 2 groups of 4 (8 loads in flight)
        #pragma unroll
        for (int gq = 0; gq < 2; ++gq) {
            float4 iv[4], tv[4];
            #pragma unroll
            for (int j = 0; j < 4; ++j) {
                const unsigned fi = base4 + (unsigned)(gq * 4 + j) * 256u + tid;
                iv[j] = in4[fi];
                tv[j] = tg4[fi];
            }
            #pragma unroll
            for (int j = 0; j < 4; ++j) {
                const unsigned idx = (unsigned)(gq * 4 + j) * 256u + tid; // 0..2047
                const unsigned row = idx >> 3, seg = idx & 7;

                float gp = fabsf(iv[j].x - tv[j].x) + fabsf(iv[j].y - tv[j].y)
                         + fabsf(iv[j].z - tv[j].z) + fabsf(iv[j].w - tv[j].w);
                // targets are exactly 0.0/1.0: BCE elem = -log(t ? p : 1-p)
                float a0 = tv[j].x > 0.5f ? iv[j].x : 1.0f - iv[j].x;
                float a1 = tv[j].y > 0.5f ? iv[j].y : 1.0f - iv[j].y;
                float a2 = tv[j].z > 0.5f ? iv[j].z : 1.0f - iv[j].z;
                float a3 = tv[j].w > 0.5f ? iv[j].w : 1.0f - iv[j].w;
                float bp = -LN2 * (__log2f(a0) + __log2f(a1)
                                 + __log2f(a2) + __log2f(a3));

                gpart[row][seg] = gp;
                bpart[row][seg] = bp;
            }
        }
        __syncthreads();

        // ---- Phase B: one row per thread
        {
            float g = 0.0f, b = 0.0f;
            #pragma unroll
            for (int k = 0; k < 8; ++k) { g += gpart[tid][k]; b += bpart[tid][k]; }
            g *= (1.0f / 32.0f);
            int bi = (int)(g * 10.0f);            // g in [0,1): trunc == floor
            bi = bi < 0 ? 0 : (bi > NBINS - 1 ? NBINS - 1 : bi);
            atomicAdd(&s_cnt[bi], 1.0f);
            atomicAdd(&s_bsum[bi], b * (1.0f / 32.0f));
        }
        __syncthreads();   // protect LDS reuse next round / hist completeness
    }

    if (tid < NBINS) {
        atomicAdd(&cnt[tid], s_cnt[tid]);
        atomicAdd(&bsum[tid], s_bsum[tid]);
    }
}

// Pass 2: finalize from the 10-bin statistics. Single thread, double math.
// sum(w) over rows == sum_b counts[b] * pbw[b]^2 (all rows in a bin share w).
__global__ void ghm_pass2(const float* __restrict__ cnt,
                          const float* __restrict__ bsum,
                          float* __restrict__ out)
{
    if (threadIdx.x == 0 && blockIdx.x == 0) {
        const double tot = (double)BS_ROWS * (double)CLA;
        // smooth = 1 - 25*(b/10)^2, zeroed for b >= 2: {1.0, 0.75, 0...}
        const float smooth[NBINS] = {1.0f, 0.75f, 0,0,0,0,0,0,0,0};
        double pbw2[NBINS];
        double sum_w = 0.0;
        for (int b = 0; b < NBINS; ++b) {
            double c = (double)cnt[b];
            double pbw = (c > 0.0 && smooth[b] > 0.0f)
                       ? (double)smooth[b] * tot / (0.25 * c) : 0.0;
            pbw2[b] = pbw * pbw;
            sum_w += c * pbw2[b];
        }
        double loss = 0.0;
        for (int b = 0; b < NBINS; ++b) {
            double w = (sum_w > 0.0) ? pbw2[b] / sum_w : 0.0;
            if (w < 1e-6) w = 0.0;   // reference: w = where(w < 1e-6, 0, w)
            loss += (double)bsum[b] * w;
        }
        out[0] = (float)loss;
    }
}

extern "C" void kernel_launch(void* const* d_in, const int* in_sizes, int n_in,
                              void* d_out, int out_size, void* d_ws, size_t ws_size,
                              hipStream_t stream) {
    const float* in = (const float*)d_in[0];   // inputs  [BS, CLA] f32
    const float* tg = (const float*)d_in[1];   // targets [BS, CLA] f32
    float* ws   = (float*)d_ws;
    float* cnt  = ws;                          // [10]
    float* bsum = ws + NBINS;                  // [10]

    // ws is poisoned (0xAA) and never re-poisoned between replays: zero it
    // ourselves every call (graph-capture-legal memset node).
    hipMemsetAsync(d_ws, 0, 2 * NBINS * sizeof(float), stream);

    ghm_pass1<<<GRID, 256, 0, stream>>>(in, tg, cnt, bsum);
    ghm_pass2<<<1, 64, 0, stream>>>(cnt, bsum, (float*)d_out);
}

// Round 5
// 80.714 us; speedup vs baseline: 1.1921x; 1.0174x over previous
//
#include <hip/hip_runtime.h>

#define BS_ROWS 1048576
#define CLA 32
#define NBINS 10
#define GRID 2048
#define RPB 512            // contiguous rows per block (GRID*RPB == BS_ROWS)
#define BATCH 8            // row-iters batched => 16 float4 loads in flight
#define OUTER 2            // BATCH*32*OUTER == RPB

// DPP-based add from a permuted lane: pure VALU, no lgkmcnt.
// CTRL must be a compile-time constant for __builtin_amdgcn_update_dpp.
template <int CTRL>
__device__ __forceinline__ float dpp_add(float v) {
    int x = __builtin_amdgcn_update_dpp(0, __float_as_int(v), CTRL, 0xF, 0xF, true);
    return v + __int_as_float(x);
}
#define DPP_XOR1 0xB1      // quad_perm [1,0,3,2]
#define DPP_XOR2 0x4E      // quad_perm [2,3,0,1]
#define DPP_HMIR 0x141     // row_half_mirror (pairs the two quads of each 8-group)

// Pass 1: 8 lanes per row (one float4 each); wave = 8 rows = 1 KiB contiguous.
// Per outer iter: 16 loads issued back-to-back (launch_bounds relaxed so the
// allocator keeps them in flight), then 8 independent compute+DPP-reduce
// chains. Row sum via 3-step DPP butterfly (xor1, xor2, half-mirror) -- all
// VALU, no LDS/ds_swizzle in the hot loop. Histogram via LDS atomics.
__global__ __launch_bounds__(256, 4) void ghm_pass1(
    const float* __restrict__ in, const float* __restrict__ tg,
    float* __restrict__ cnt, float* __restrict__ bsum)
{
    __shared__ float s_cnt[NBINS];
    __shared__ float s_bsum[NBINS];
    const int tid = threadIdx.x;
    if (tid < NBINS) { s_cnt[tid] = 0.0f; s_bsum[tid] = 0.0f; }
    __syncthreads();

    const unsigned sub = tid & 7;             // float4 segment within row
    const unsigned rg  = tid >> 3;            // row-group 0..31
    const float4* __restrict__ in4 = (const float4*)in;
    const float4* __restrict__ tg4 = (const float4*)tg;
    const unsigned base = blockIdx.x * (RPB * CLA / 4);   // block's float4 base

    #pragma unroll 1
    for (int outer = 0; outer < OUTER; ++outer) {
        // ---- issue all 16 loads before any compute
        float4 iv[BATCH], tv[BATCH];
        #pragma unroll
        for (int j = 0; j < BATCH; ++j) {
            const unsigned fi = base + (unsigned)(outer * BATCH + j) * 256u
                              + rg * 8u + sub;            // = ... + lane (coalesced)
            iv[j] = in4[fi];
            tv[j] = tg4[fi];
        }

        // ---- 8 independent compute + DPP-reduce chains
        float garr[BATCH], barr[BATCH];
        #pragma unroll
        for (int j = 0; j < BATCH; ++j) {
            float gp = fabsf(iv[j].x - tv[j].x) + fabsf(iv[j].y - tv[j].y)
                     + fabsf(iv[j].z - tv[j].z) + fabsf(iv[j].w - tv[j].w);
            // targets are exactly 0.0/1.0: BCE elem = -log(t ? p : 1-p)
            float a0 = tv[j].x > 0.5f ? iv[j].x : 1.0f - iv[j].x;
            float a1 = tv[j].y > 0.5f ? iv[j].y : 1.0f - iv[j].y;
            float a2 = tv[j].z > 0.5f ? iv[j].z : 1.0f - iv[j].z;
            float a3 = tv[j].w > 0.5f ? iv[j].w : 1.0f - iv[j].w;
            float bp = -(__logf(a0) + __logf(a1) + __logf(a2) + __logf(a3));

            gp = dpp_add<DPP_XOR1>(gp);  bp = dpp_add<DPP_XOR1>(bp);
            gp = dpp_add<DPP_XOR2>(gp);  bp = dpp_add<DPP_XOR2>(bp);
            gp = dpp_add<DPP_HMIR>(gp);  bp = dpp_add<DPP_HMIR>(bp);
            garr[j] = gp;  barr[j] = bp;
        }

        // ---- one divergent region: seg-0 lanes bin their 8 rows
        if (sub == 0) {
            #pragma unroll
            for (int j = 0; j < BATCH; ++j) {
                float g = garr[j] * (1.0f / 32.0f);
                int bi = (int)(g * 10.0f);        // g in [0,1]: trunc == floor
                bi = bi < 0 ? 0 : (bi > NBINS - 1 ? NBINS - 1 : bi);
                atomicAdd(&s_cnt[bi], 1.0f);
                atomicAdd(&s_bsum[bi], barr[j] * (1.0f / 32.0f));
            }
        }
    }

    __syncthreads();
    if (tid < NBINS) {
        atomicAdd(&cnt[tid], s_cnt[tid]);
        atomicAdd(&bsum[tid], s_bsum[tid]);
    }
}

// Pass 2: finalize from the 10-bin statistics. Single thread, double math.
// sum(w) over rows == sum_b counts[b] * pbw[b]^2 (all rows in a bin share w).
__global__ void ghm_pass2(const float* __restrict__ cnt,
                          const float* __restrict__ bsum,
                          float* __restrict__ out)
{
    if (threadIdx.x == 0 && blockIdx.x == 0) {
        const double tot = (double)BS_ROWS * (double)CLA;
        // smooth = 1 - 25*(b/10)^2, zeroed for b >= 2: {1.0, 0.75, 0...}
        const float smooth[NBINS] = {1.0f, 0.75f, 0,0,0,0,0,0,0,0};
        double pbw2[NBINS];
        double sum_w = 0.0;
        for (int b = 0; b < NBINS; ++b) {
            double c = (double)cnt[b];
            double pbw = (c > 0.0 && smooth[b] > 0.0f)
                       ? (double)smooth[b] * tot / (0.25 * c) : 0.0;
            pbw2[b] = pbw * pbw;
            sum_w += c * pbw2[b];
        }
        double loss = 0.0;
        for (int b = 0; b < NBINS; ++b) {
            double w = (sum_w > 0.0) ? pbw2[b] / sum_w : 0.0;
            if (w < 1e-6) w = 0.0;   // reference: w = where(w < 1e-6, 0, w)
            loss += (double)bsum[b] * w;
        }
        out[0] = (float)loss;
    }
}

extern "C" void kernel_launch(void* const* d_in, const int* in_sizes, int n_in,
                              void* d_out, int out_size, void* d_ws, size_t ws_size,
                              hipStream_t stream) {
    const float* in = (const float*)d_in[0];   // inputs  [BS, CLA] f32
    const float* tg = (const float*)d_in[1];   // targets [BS, CLA] f32
    float* ws   = (float*)d_ws;
    float* cnt  = ws;                          // [10]
    float* bsum = ws + NBINS;                  // [10]

    // ws is poisoned (0xAA) and never re-poisoned between replays: zero it
    // ourselves every call (graph-capture-legal memset node).
    (void)hipMemsetAsync(d_ws, 0, 2 * NBINS * sizeof(float), stream);

    ghm_pass1<<<GRID, 256, 0, stream>>>(in, tg, cnt, bsum);
    ghm_pass2<<<1, 64, 0, stream>>>(cnt, bsum, (float*)d_out);
}